// Round 3
// baseline (3453.627 us; speedup 1.0000x reference)
//
#include <hip/hip_runtime.h>

typedef unsigned int  u32;
typedef unsigned short u16;
typedef _Float16 half8 __attribute__((ext_vector_type(8)));
typedef short   short8 __attribute__((ext_vector_type(8)));
typedef float   f32x4  __attribute__((ext_vector_type(4)));

#define T_LEN 512
#define BATCH 64
#define EDIM  256
#define HDIM  256
#define G4    1024   // 4*H gate rows

// ---------- numeric helpers ----------
static __device__ __forceinline__ u16 f2bf(float f) {
  u32 u = __builtin_bit_cast(u32, f);
  u = (u + 0x7fffu + ((u >> 16) & 1u)) >> 16;   // RTNE
  return (u16)u;
}
static __device__ __forceinline__ u16 f2h(float a) {
  _Float16 ha = (_Float16)a;
  return __builtin_bit_cast(u16, ha);
}
static __device__ __forceinline__ float h2f(u16 a) {
  return (float)__builtin_bit_cast(_Float16, a);
}
static __device__ __forceinline__ float sigf(float x) {
  return 1.0f / (1.0f + __expf(-x));
}
static __device__ __forceinline__ float tanhfast(float x) {
  return 2.0f / (1.0f + __expf(-2.0f * x)) - 1.0f;
}

// ---------- kernel 1: pack W_hh_f (f32 [1024x256]) into f16 MFMA A-frag order --
// Wf[mt][kt][lane][j] f16, flat ((mt*8+kt)*64+lane)*8+j.
// Value = W[mt*16 + (lane&15)][kt*32 + (lane>>4)*8 + j].
__global__ __launch_bounds__(256) void k_prep(const float* __restrict__ whh,
                                              u16* __restrict__ Wf) {
  int cell = blockIdx.x * 256 + threadIdx.x;  // 32768 cells, 8 f16 each
  int mt = cell >> 9, kt = (cell >> 6) & 7, l = cell & 63;
  int gr = mt * 16 + (l & 15);
  int c0 = kt * 32 + (l >> 4) * 8;
  const float4* src = (const float4*)(whh + (size_t)gr * 256 + c0);
  float4 a = src[0], b = src[1];
  u16 o[8] = { f2h(a.x), f2h(a.y), f2h(a.z), f2h(a.w),
               f2h(b.x), f2h(b.y), f2h(b.z), f2h(b.w) };
  uint4* dst = (uint4*)(Wf + (size_t)cell * 8);
  *dst = *(uint4*)o;
}

// ---------- kernel 2: xproj via bf16 MFMA, output f16 in k_rnn D-frag order ---
// xp2[t][bg][mt][lane][r], flat ((((t*4+bg)*64+mt)*64+lane)*4+r), f16.
#define LDSPITCH 264
__global__ __launch_bounds__(256) void k_xproj(const int* __restrict__ x,
                                               const float* __restrict__ emb,
                                               const float* __restrict__ wih,
                                               const float* __restrict__ bih,
                                               const float* __restrict__ bhh,
                                               u16* __restrict__ xp2) {
  __shared__ u16 smA[64 * LDSPITCH];
  __shared__ u16 smB[64 * LDSPITCH];
  const int tn = blockIdx.x, t = blockIdx.y;
  const int tid = threadIdx.x;
  const int r = tid >> 2, q4 = tid & 3;

  { // stage A: emb rows (batch r, timestep t), fp32 -> bf16
    int eidx = x[r * T_LEN + t];
    const float4* src = (const float4*)(emb + (size_t)eidx * EDIM + q4 * 64);
    u16* dst = smA + r * LDSPITCH + q4 * 64;
    #pragma unroll
    for (int i = 0; i < 16; ++i) {
      float4 v = src[i];
      uint2 p;
      p.x = (u32)f2bf(v.x) | ((u32)f2bf(v.y) << 16);
      p.y = (u32)f2bf(v.z) | ((u32)f2bf(v.w) << 16);
      *(uint2*)&dst[i * 4] = p;
    }
  }
  { // stage B: w_ih rows g = tn*64 + r
    const float4* src = (const float4*)(wih + (size_t)(tn * 64 + r) * EDIM + q4 * 64);
    u16* dst = smB + r * LDSPITCH + q4 * 64;
    #pragma unroll
    for (int i = 0; i < 16; ++i) {
      float4 v = src[i];
      uint2 p;
      p.x = (u32)f2bf(v.x) | ((u32)f2bf(v.y) << 16);
      p.y = (u32)f2bf(v.z) | ((u32)f2bf(v.w) << 16);
      *(uint2*)&dst[i * 4] = p;
    }
  }
  __syncthreads();

  const int wv = tid >> 6, lane = tid & 63;
  const int lm = lane & 15, q = lane >> 4;
  f32x4 acc[4];
  #pragma unroll
  for (int nt = 0; nt < 4; ++nt) acc[nt] = (f32x4){0.f, 0.f, 0.f, 0.f};

  const u16* pa = smA + (wv * 16 + lm) * LDSPITCH + q * 8;
  const u16* pb = smB + lm * LDSPITCH + q * 8;
  #pragma unroll
  for (int ks = 0; ks < 8; ++ks) {
    short8 av = *(const short8*)(pa + ks * 32);
    #pragma unroll
    for (int nt = 0; nt < 4; ++nt) {
      short8 bv = *(const short8*)(pb + nt * 16 * LDSPITCH + ks * 32);
      acc[nt] = __builtin_amdgcn_mfma_f32_16x16x32_bf16(av, bv, acc[nt], 0, 0, 0);
    }
  }
  // D: row = batch = wv*16 + q*4 + rr, col = gate = tn*64 + nt*16 + lm.
  #pragma unroll
  for (int nt = 0; nt < 4; ++nt) {
    int g = tn * 64 + nt * 16 + lm;
    float bias = bih[g] + bhh[g];
    int mt = g >> 4, qd = (g & 15) >> 2, rb = g & 3;
    #pragma unroll
    for (int rr = 0; rr < 4; ++rr) {
      int bl = q * 4 + rr;   // batch-in-group; bg = wv
      size_t idx = ((((size_t)t * 4 + wv) * 64 + mt) * 64 + (qd * 16 + bl)) * 4 + rb;
      xp2[idx] = f2h(acc[nt][rr] + bias);
    }
  }
}

// ---------- kernel 3: recurrence, 8 WGs x 256 thr, weights REGISTER-resident --
// WG g owns m-tiles mt = q*16 + g*2 + j (q=gate 0..3, j=0..1) -> h rows
// g*32..g*32+31. Wave w = batch n-tile. Per-step h exchange via global hbuf
// (double-buffered) + agent-scope release/acquire flags.
__global__ __launch_bounds__(256, 1) void k_rnn(const u16* __restrict__ Wf,
                                                const u16* __restrict__ xp2,
                                                u16* __restrict__ hbuf,
                                                unsigned* __restrict__ flags,
                                                float* __restrict__ hf) {
  __shared__ u16 smH[64 * 256];   // 32 KB, swizzled [batch][chunk^]
  const int g = blockIdx.x;
  const int tid = threadIdx.x;
  const int w = tid >> 6, l = tid & 63;    // w = n-tile (batch group)
  const int bl = l & 15, qd = l >> 4;
  const int batch = w * 16 + bl;

  // resident weights: Wr[q*2+j][kt], 64 frags = 256 VGPRs/thread
  half8 Wr[8][8];
  #pragma unroll
  for (int q = 0; q < 4; ++q)
    #pragma unroll
    for (int j = 0; j < 2; ++j) {
      int mt = q * 16 + g * 2 + j;
      #pragma unroll
      for (int kt = 0; kt < 8; ++kt)
        Wr[q * 2 + j][kt] = *(const half8*)(Wf + ((size_t)(mt * 8 + kt) * 64 + l) * 8);
    }

  float c[8];
  #pragma unroll
  for (int i = 0; i < 8; ++i) c[i] = 0.f;

  const int sb = tid >> 2, sc0 = (tid & 3) * 8;   // stager role: batch, chunk base

  for (int t = 0; t < T_LEN; ++t) {
    // 1. wait until all WGs published h for this step (acquire -> cache inv)
    if (t > 0) {
      if (tid < 64) {
        for (;;) {
          int ok = 1;
          #pragma unroll
          for (int i = 0; i < 8; ++i)
            ok &= (__hip_atomic_load(&flags[i], __ATOMIC_ACQUIRE,
                                     __HIP_MEMORY_SCOPE_AGENT) >= (unsigned)t);
          if (ok) break;
          __builtin_amdgcn_s_sleep(2);
        }
      }
      __syncthreads();
    }

    // 2. issue xp loads early (consumed after MFMA loop)
    uint2 xv[8];
    {
      const u16* xb = xp2 + ((size_t)t * 4 + w) * 16384 + (size_t)l * 4;
      #pragma unroll
      for (int q = 0; q < 4; ++q)
        #pragma unroll
        for (int j = 0; j < 2; ++j)
          xv[q * 2 + j] = *(const uint2*)(xb + (size_t)(q * 16 + g * 2 + j) * 256);
    }

    // 3. stage hbuf[t&1] -> LDS with XOR swizzle (conflict-free b128 reads)
    {
      const u16* src = hbuf + (t & 1) * 16384 + sb * 256 + sc0 * 8;
      #pragma unroll
      for (int k = 0; k < 8; ++k) {
        uint4 v = *(const uint4*)(src + k * 8);
        int cc = (sc0 + k) ^ (sb & 7);
        *(uint4*)(smH + sb * 256 + cc * 8) = v;
      }
    }
    __syncthreads();

    // 4. MFMA: 8 m-tiles x 1 n-tile x 8 kt
    f32x4 acc[8];
    #pragma unroll
    for (int i = 0; i < 8; ++i) acc[i] = (f32x4){0.f, 0.f, 0.f, 0.f};
    #pragma unroll
    for (int kt = 0; kt < 8; ++kt) {
      int cc = (kt * 4 + qd) ^ (bl & 7);
      half8 Bf = *(const half8*)(smH + batch * 256 + cc * 8);
      #pragma unroll
      for (int i = 0; i < 8; ++i)
        acc[i] = __builtin_amdgcn_mfma_f32_16x16x32_f16(Wr[i][kt], Bf, acc[i], 0, 0, 0);
    }

    // 5. fold xp term
    #pragma unroll
    for (int i = 0; i < 8; ++i) {
      acc[i][0] += h2f((u16)(xv[i].x & 0xffff));
      acc[i][1] += h2f((u16)(xv[i].x >> 16));
      acc[i][2] += h2f((u16)(xv[i].y & 0xffff));
      acc[i][3] += h2f((u16)(xv[i].y >> 16));
    }

    // 6. gates + h-update; store h rows g*32+j*16+qd*4+r for this batch
    u16* hw = hbuf + ((t + 1) & 1) * 16384;
    #pragma unroll
    for (int j = 0; j < 2; ++j) {
      u16 hh[4];
      #pragma unroll
      for (int r = 0; r < 4; ++r) {
        float zi = acc[0 + j][r], zf = acc[2 + j][r];
        float zg = acc[4 + j][r], zo = acc[6 + j][r];
        int ci = j * 4 + r;
        c[ci] = sigf(zf) * c[ci] + sigf(zi) * tanhfast(zg);
        float hn = sigf(zo) * tanhfast(c[ci]);
        hh[r] = f2h(hn);
        if (t == T_LEN - 1)
          hf[(size_t)batch * 256 + g * 32 + j * 16 + qd * 4 + r] = hn;
      }
      *(uint2*)(hw + (size_t)batch * 256 + g * 32 + j * 16 + qd * 4) = *(uint2*)hh;
    }
    __syncthreads();   // drains vmcnt: all WG stores complete before release

    // 7. publish (release: L2 writeback + flag store)
    if (tid == 0 && t < T_LEN - 1)
      __hip_atomic_store(&flags[g], (unsigned)(t + 1), __ATOMIC_RELEASE,
                         __HIP_MEMORY_SCOPE_AGENT);
  }
}

// ---------- kernel 4: backward single step + fc1 + fc2 ----------
__global__ __launch_bounds__(256) void k_tail(const int* __restrict__ x,
                                              const float* __restrict__ emb,
                                              const float* __restrict__ wihb,
                                              const float* __restrict__ bihb,
                                              const float* __restrict__ bhhb,
                                              const float* __restrict__ fc1w,
                                              const float* __restrict__ fc1b,
                                              const float* __restrict__ fc2w,
                                              const float* __restrict__ fc2b,
                                              const float* __restrict__ hf,
                                              float* __restrict__ out) {
  const int b = blockIdx.x, tid = threadIdx.x;
  __shared__ float e[EDIM], hb[HDIM], hfl[HDIM], f1[24];
  e[tid]   = emb[(size_t)x[b * T_LEN + (T_LEN - 1)] * EDIM + tid];
  hfl[tid] = hf[b * HDIM + tid];
  __syncthreads();

  float z[4];
  #pragma unroll
  for (int gq = 0; gq < 4; ++gq) {
    int g = gq * HDIM + tid;
    float s = bihb[g] + bhhb[g];
    const float4* wr = (const float4*)(wihb + (size_t)g * EDIM);
    #pragma unroll 8
    for (int k = 0; k < 64; ++k) {
      float4 w = wr[k];
      s += w.x * e[4 * k] + w.y * e[4 * k + 1] + w.z * e[4 * k + 2] + w.w * e[4 * k + 3];
    }
    z[gq] = s;
  }
  float cb = sigf(z[0]) * tanhfast(z[2]);   // c0 = 0
  hb[tid] = sigf(z[3]) * tanhfast(cb);
  __syncthreads();

  if (tid < 24) {
    float s = fc1b[tid];
    const float* w = fc1w + tid * 512;
    #pragma unroll 8
    for (int k = 0; k < HDIM; ++k) s += w[k] * hfl[k] + w[HDIM + k] * hb[k];
    f1[tid] = fmaxf(s, 0.f);
  }
  __syncthreads();
  if (tid < 2) {
    float s = fc2b[tid];
    #pragma unroll
    for (int k = 0; k < 24; ++k) s += fc2w[tid * 24 + k] * f1[k];
    out[b * 2 + tid] = s;
  }
}

// ---------- launch ----------
extern "C" void kernel_launch(void* const* d_in, const int* in_sizes, int n_in,
                              void* d_out, int out_size, void* d_ws, size_t ws_size,
                              hipStream_t stream) {
  const int*   x     = (const int*)  d_in[0];
  const float* emb   = (const float*)d_in[1];
  const float* wih_f = (const float*)d_in[2];
  const float* whh_f = (const float*)d_in[3];
  const float* bih_f = (const float*)d_in[4];
  const float* bhh_f = (const float*)d_in[5];
  const float* wih_b = (const float*)d_in[6];
  // d_in[7] = w_hh_b: unused (backward runs exactly one step from zero state)
  const float* bih_b = (const float*)d_in[8];
  const float* bhh_b = (const float*)d_in[9];
  const float* fc1w  = (const float*)d_in[10];
  const float* fc1b  = (const float*)d_in[11];
  const float* fc2w  = (const float*)d_in[12];
  const float* fc2b  = (const float*)d_in[13];
  float* out = (float*)d_out;

  // workspace: xp2 64 MiB | Wf 512 KiB | hf 64 KiB | hbuf 64 KiB | flags 64 B
  char* ws = (char*)d_ws;
  u16*      xp2   = (u16*)ws;
  u16*      Wf    = (u16*)(ws + 67108864);
  float*    hf    = (float*)(ws + 67108864 + 524288);
  u16*      hbuf  = (u16*)(ws + 67108864 + 524288 + 65536);
  unsigned* flags = (unsigned*)(ws + 67108864 + 524288 + 65536 + 65536);

  // zero h0 (both parity buffers) and the sync flags (ws is poisoned 0xAA)
  hipMemsetAsync(hbuf, 0, 65536 + 64, stream);

  k_prep <<<128, 256, 0, stream>>>(whh_f, Wf);
  k_xproj<<<dim3(16, 512), 256, 0, stream>>>(x, emb, wih_f, bih_f, bhh_f, xp2);
  k_rnn  <<<8, 256, 0, stream>>>(Wf, xp2, hbuf, flags, hf);
  k_tail <<<BATCH, 256, 0, stream>>>(x, emb, wih_b, bih_b, bhh_b,
                                     fc1w, fc1b, fc2w, fc2b, hf, out);
}

// Round 4
// 2461.752 us; speedup vs baseline: 1.4029x; 1.4029x over previous
//
#include <hip/hip_runtime.h>

typedef unsigned int  u32;
typedef unsigned short u16;
typedef unsigned long long u64;
typedef _Float16 half8 __attribute__((ext_vector_type(8)));
typedef short   short8 __attribute__((ext_vector_type(8)));
typedef float   f32x4  __attribute__((ext_vector_type(4)));

#define T_LEN 512
#define BATCH 64
#define EDIM  256
#define HDIM  256
#define G4    1024   // 4*H gate rows

// ---------- numeric helpers ----------
static __device__ __forceinline__ u16 f2bf(float f) {
  u32 u = __builtin_bit_cast(u32, f);
  u = (u + 0x7fffu + ((u >> 16) & 1u)) >> 16;   // RTNE
  return (u16)u;
}
static __device__ __forceinline__ u16 f2h(float a) {
  _Float16 ha = (_Float16)a;
  return __builtin_bit_cast(u16, ha);
}
static __device__ __forceinline__ float h2f(u16 a) {
  return (float)__builtin_bit_cast(_Float16, a);
}
static __device__ __forceinline__ float sigf(float x) {
  return 1.0f / (1.0f + __expf(-x));
}
static __device__ __forceinline__ float tanhfast(float x) {
  return 2.0f / (1.0f + __expf(-2.0f * x)) - 1.0f;
}

// ---------- kernel 1: pack W_hh_f (f32 [1024x256]) into f16 MFMA A-frag order --
// Wf[mt][kt][lane][j] f16, flat ((mt*8+kt)*64+lane)*8+j.
// Value = W[mt*16 + (lane&15)][kt*32 + (lane>>4)*8 + j].
__global__ __launch_bounds__(256) void k_prep(const float* __restrict__ whh,
                                              u16* __restrict__ Wf) {
  int cell = blockIdx.x * 256 + threadIdx.x;  // 32768 cells, 8 f16 each
  int mt = cell >> 9, kt = (cell >> 6) & 7, l = cell & 63;
  int gr = mt * 16 + (l & 15);
  int c0 = kt * 32 + (l >> 4) * 8;
  const float4* src = (const float4*)(whh + (size_t)gr * 256 + c0);
  float4 a = src[0], b = src[1];
  u16 o[8] = { f2h(a.x), f2h(a.y), f2h(a.z), f2h(a.w),
               f2h(b.x), f2h(b.y), f2h(b.z), f2h(b.w) };
  uint4* dst = (uint4*)(Wf + (size_t)cell * 8);
  *dst = *(uint4*)o;
}

// ---------- kernel 2: xproj via bf16 MFMA, output f16 in k_rnn D-frag order ---
// xp2[t][bg][mt][lane][r], flat ((((t*4+bg)*64+mt)*64+lane)*4+r), f16.
#define LDSPITCH 264
__global__ __launch_bounds__(256) void k_xproj(const int* __restrict__ x,
                                               const float* __restrict__ emb,
                                               const float* __restrict__ wih,
                                               const float* __restrict__ bih,
                                               const float* __restrict__ bhh,
                                               u16* __restrict__ xp2) {
  __shared__ u16 smA[64 * LDSPITCH];
  __shared__ u16 smB[64 * LDSPITCH];
  const int tn = blockIdx.x, t = blockIdx.y;
  const int tid = threadIdx.x;
  const int r = tid >> 2, q4 = tid & 3;

  { // stage A: emb rows (batch r, timestep t), fp32 -> bf16
    int eidx = x[r * T_LEN + t];
    const float4* src = (const float4*)(emb + (size_t)eidx * EDIM + q4 * 64);
    u16* dst = smA + r * LDSPITCH + q4 * 64;
    #pragma unroll
    for (int i = 0; i < 16; ++i) {
      float4 v = src[i];
      uint2 p;
      p.x = (u32)f2bf(v.x) | ((u32)f2bf(v.y) << 16);
      p.y = (u32)f2bf(v.z) | ((u32)f2bf(v.w) << 16);
      *(uint2*)&dst[i * 4] = p;
    }
  }
  { // stage B: w_ih rows g = tn*64 + r
    const float4* src = (const float4*)(wih + (size_t)(tn * 64 + r) * EDIM + q4 * 64);
    u16* dst = smB + r * LDSPITCH + q4 * 64;
    #pragma unroll
    for (int i = 0; i < 16; ++i) {
      float4 v = src[i];
      uint2 p;
      p.x = (u32)f2bf(v.x) | ((u32)f2bf(v.y) << 16);
      p.y = (u32)f2bf(v.z) | ((u32)f2bf(v.w) << 16);
      *(uint2*)&dst[i * 4] = p;
    }
  }
  __syncthreads();

  const int wv = tid >> 6, lane = tid & 63;
  const int lm = lane & 15, q = lane >> 4;
  f32x4 acc[4];
  #pragma unroll
  for (int nt = 0; nt < 4; ++nt) acc[nt] = (f32x4){0.f, 0.f, 0.f, 0.f};

  const u16* pa = smA + (wv * 16 + lm) * LDSPITCH + q * 8;
  const u16* pb = smB + lm * LDSPITCH + q * 8;
  #pragma unroll
  for (int ks = 0; ks < 8; ++ks) {
    short8 av = *(const short8*)(pa + ks * 32);
    #pragma unroll
    for (int nt = 0; nt < 4; ++nt) {
      short8 bv = *(const short8*)(pb + nt * 16 * LDSPITCH + ks * 32);
      acc[nt] = __builtin_amdgcn_mfma_f32_16x16x32_bf16(av, bv, acc[nt], 0, 0, 0);
    }
  }
  // D: row = batch = wv*16 + q*4 + rr, col = gate = tn*64 + nt*16 + lm.
  #pragma unroll
  for (int nt = 0; nt < 4; ++nt) {
    int g = tn * 64 + nt * 16 + lm;
    float bias = bih[g] + bhh[g];
    int mt = g >> 4, qd = (g & 15) >> 2, rb = g & 3;
    #pragma unroll
    for (int rr = 0; rr < 4; ++rr) {
      int bl = q * 4 + rr;   // batch-in-group; bg = wv
      size_t idx = ((((size_t)t * 4 + wv) * 64 + mt) * 64 + (qd * 16 + bl)) * 4 + rb;
      xp2[idx] = f2h(acc[nt][rr] + bias);
    }
  }
}

// ---------- kernel 3: recurrence, 16 WGs x 256 thr, weights VGPR-resident ----
// WG g owns m-tiles mt = q*16 + g (q = gate 0..3) -> h rows [g*16, g*16+16).
// Wave w = batch n-tile. h exchange via relaxed agent-scope (sc1) atomics on
// hbuf/flags ONLY -> no cache invalidation, weights stay in VGPRs, xp2 in L2.
__global__ __launch_bounds__(256, 2) void k_rnn(const u16* __restrict__ Wf,
                                                const u16* __restrict__ xp2,
                                                u16* __restrict__ hbuf,
                                                unsigned* __restrict__ flags,
                                                float* __restrict__ hf) {
  const int g = blockIdx.x;          // 0..15
  const int tid = threadIdx.x;
  const int w = tid >> 6, l = tid & 63;
  const int bl = l & 15, qd = l >> 4;
  const int batch = w * 16 + bl;

  // resident weights: 4 gates x 8 kt = 32 frags = 128 VGPRs
  half8 Wr[4][8];
  #pragma unroll
  for (int q = 0; q < 4; ++q)
    #pragma unroll
    for (int kt = 0; kt < 8; ++kt)
      Wr[q][kt] = *(const half8*)(Wf + ((size_t)((q * 16 + g) * 8 + kt) * 64 + l) * 8);
  // opacity barrier: values become unknown -> rematerialization from Wf illegal
  #pragma unroll
  for (int q = 0; q < 4; ++q)
    asm volatile("" : "+v"(Wr[q][0]), "+v"(Wr[q][1]), "+v"(Wr[q][2]), "+v"(Wr[q][3]),
                      "+v"(Wr[q][4]), "+v"(Wr[q][5]), "+v"(Wr[q][6]), "+v"(Wr[q][7]));

  float c[4];
  #pragma unroll
  for (int r = 0; r < 4; ++r) c[r] = 0.f;

  u64* hb64 = (u64*)hbuf;
  const int hrd = batch * 64 + qd * 2;        // + kt*8 : B-frag base (u64 units)
  const int hwr = batch * 64 + g * 4 + qd;    // h-write slot (u64 units)

  for (int t = 0; t < T_LEN; ++t) {
    // 1. wait for all WGs to have published h(t)
    if (t > 0) {
      const unsigned tt = (unsigned)t;
      while (__hip_atomic_load(&flags[tid & 15], __ATOMIC_RELAXED,
                               __HIP_MEMORY_SCOPE_AGENT) < tt)
        __builtin_amdgcn_s_sleep(1);
      __syncthreads();
    }

    // 2. B-frag loads: h[batch][k] direct from coherence point (sc1)
    u64* hb = hb64 + (t & 1) * 8192;
    u64 hv[8][2];
    #pragma unroll
    for (int kt = 0; kt < 8; ++kt) {
      hv[kt][0] = __hip_atomic_load(hb + hrd + kt * 8,     __ATOMIC_RELAXED,
                                    __HIP_MEMORY_SCOPE_AGENT);
      hv[kt][1] = __hip_atomic_load(hb + hrd + kt * 8 + 1, __ATOMIC_RELAXED,
                                    __HIP_MEMORY_SCOPE_AGENT);
    }

    // 3. xp loads (plain, L2/L3-cached)
    uint2 xv[4];
    {
      const u16* xb = xp2 + ((size_t)t * 4 + w) * 16384 + (size_t)l * 4;
      #pragma unroll
      for (int q = 0; q < 4; ++q)
        xv[q] = *(const uint2*)(xb + (size_t)(q * 16 + g) * 256);
    }

    // 4. MFMA: 4 m-tiles x 8 kt
    f32x4 acc[4];
    #pragma unroll
    for (int q = 0; q < 4; ++q) acc[q] = (f32x4){0.f, 0.f, 0.f, 0.f};
    #pragma unroll
    for (int kt = 0; kt < 8; ++kt) {
      u64 b2[2] = { hv[kt][0], hv[kt][1] };
      half8 Bf = *(half8*)b2;
      #pragma unroll
      for (int q = 0; q < 4; ++q)
        acc[q] = __builtin_amdgcn_mfma_f32_16x16x32_f16(Wr[q][kt], Bf, acc[q], 0, 0, 0);
    }

    // 5. fold xp term
    #pragma unroll
    for (int q = 0; q < 4; ++q) {
      acc[q][0] += h2f((u16)(xv[q].x & 0xffff));
      acc[q][1] += h2f((u16)(xv[q].x >> 16));
      acc[q][2] += h2f((u16)(xv[q].y & 0xffff));
      acc[q][3] += h2f((u16)(xv[q].y >> 16));
    }

    // 6. gates + h-update for rows g*16 + qd*4 + r, batch bl of group w
    u16 hh[4];
    #pragma unroll
    for (int r = 0; r < 4; ++r) {
      float zi = acc[0][r], zf = acc[1][r], zg = acc[2][r], zo = acc[3][r];
      c[r] = sigf(zf) * c[r] + sigf(zi) * tanhfast(zg);
      float hn = sigf(zo) * tanhfast(c[r]);
      hh[r] = f2h(hn);
      if (t == T_LEN - 1)
        hf[(size_t)batch * 256 + g * 16 + qd * 4 + r] = hn;
    }
    __hip_atomic_store(hb64 + ((t + 1) & 1) * 8192 + hwr, *(u64*)hh,
                       __ATOMIC_RELAXED, __HIP_MEMORY_SCOPE_AGENT);

    // 7. publish: drain stores, WG-wide, then bump flag
    asm volatile("s_waitcnt vmcnt(0)" ::: "memory");
    __syncthreads();
    if (tid == 0 && t < T_LEN - 1)
      __hip_atomic_store(&flags[g], (unsigned)(t + 1), __ATOMIC_RELAXED,
                         __HIP_MEMORY_SCOPE_AGENT);
  }
}

// ---------- kernel 4: backward single step + fc1 + fc2 ----------
__global__ __launch_bounds__(256) void k_tail(const int* __restrict__ x,
                                              const float* __restrict__ emb,
                                              const float* __restrict__ wihb,
                                              const float* __restrict__ bihb,
                                              const float* __restrict__ bhhb,
                                              const float* __restrict__ fc1w,
                                              const float* __restrict__ fc1b,
                                              const float* __restrict__ fc2w,
                                              const float* __restrict__ fc2b,
                                              const float* __restrict__ hf,
                                              float* __restrict__ out) {
  const int b = blockIdx.x, tid = threadIdx.x;
  __shared__ float e[EDIM], hb[HDIM], hfl[HDIM], f1[24];
  e[tid]   = emb[(size_t)x[b * T_LEN + (T_LEN - 1)] * EDIM + tid];
  hfl[tid] = hf[b * HDIM + tid];
  __syncthreads();

  float z[4];
  #pragma unroll
  for (int gq = 0; gq < 4; ++gq) {
    int g = gq * HDIM + tid;
    float s = bihb[g] + bhhb[g];
    const float4* wr = (const float4*)(wihb + (size_t)g * EDIM);
    #pragma unroll 8
    for (int k = 0; k < 64; ++k) {
      float4 w = wr[k];
      s += w.x * e[4 * k] + w.y * e[4 * k + 1] + w.z * e[4 * k + 2] + w.w * e[4 * k + 3];
    }
    z[gq] = s;
  }
  float cb = sigf(z[0]) * tanhfast(z[2]);   // c0 = 0
  hb[tid] = sigf(z[3]) * tanhfast(cb);
  __syncthreads();

  if (tid < 24) {
    float s = fc1b[tid];
    const float* w = fc1w + tid * 512;
    #pragma unroll 8
    for (int k = 0; k < HDIM; ++k) s += w[k] * hfl[k] + w[HDIM + k] * hb[k];
    f1[tid] = fmaxf(s, 0.f);
  }
  __syncthreads();
  if (tid < 2) {
    float s = fc2b[tid];
    #pragma unroll
    for (int k = 0; k < 24; ++k) s += fc2w[tid * 24 + k] * f1[k];
    out[b * 2 + tid] = s;
  }
}

// ---------- launch ----------
extern "C" void kernel_launch(void* const* d_in, const int* in_sizes, int n_in,
                              void* d_out, int out_size, void* d_ws, size_t ws_size,
                              hipStream_t stream) {
  const int*   x     = (const int*)  d_in[0];
  const float* emb   = (const float*)d_in[1];
  const float* wih_f = (const float*)d_in[2];
  const float* whh_f = (const float*)d_in[3];
  const float* bih_f = (const float*)d_in[4];
  const float* bhh_f = (const float*)d_in[5];
  const float* wih_b = (const float*)d_in[6];
  // d_in[7] = w_hh_b: unused (backward runs exactly one step from zero state)
  const float* bih_b = (const float*)d_in[8];
  const float* bhh_b = (const float*)d_in[9];
  const float* fc1w  = (const float*)d_in[10];
  const float* fc1b  = (const float*)d_in[11];
  const float* fc2w  = (const float*)d_in[12];
  const float* fc2b  = (const float*)d_in[13];
  float* out = (float*)d_out;

  // workspace: xp2 64 MiB | Wf 512 KiB | hf 64 KiB | hbuf 64 KiB | flags 64 B
  char* ws = (char*)d_ws;
  u16*      xp2   = (u16*)ws;
  u16*      Wf    = (u16*)(ws + 67108864);
  float*    hf    = (float*)(ws + 67108864 + 524288);
  u16*      hbuf  = (u16*)(ws + 67108864 + 524288 + 65536);
  unsigned* flags = (unsigned*)(ws + 67108864 + 524288 + 65536 + 65536);

  // zero h0 (both parity buffers) and the sync flags (ws is poisoned 0xAA)
  hipMemsetAsync(hbuf, 0, 65536 + 64, stream);

  k_prep <<<128, 256, 0, stream>>>(whh_f, Wf);
  k_xproj<<<dim3(16, 512), 256, 0, stream>>>(x, emb, wih_f, bih_f, bhh_f, xp2);
  k_rnn  <<<16, 256, 0, stream>>>(Wf, xp2, hbuf, flags, hf);
  k_tail <<<BATCH, 256, 0, stream>>>(x, emb, wih_b, bih_b, bhh_b,
                                     fc1w, fc1b, fc2w, fc2b, hf, out);
}

// Round 5
// 2458.089 us; speedup vs baseline: 1.4050x; 1.0015x over previous
//
#include <hip/hip_runtime.h>

typedef unsigned int  u32;
typedef unsigned short u16;
typedef unsigned long long u64;
typedef _Float16 half8 __attribute__((ext_vector_type(8)));
typedef short   short8 __attribute__((ext_vector_type(8)));
typedef float   f32x4  __attribute__((ext_vector_type(4)));

#define T_LEN 512
#define BATCH 64
#define EDIM  256
#define HDIM  256
#define G4    1024   // 4*H gate rows

// ---------- numeric helpers ----------
static __device__ __forceinline__ u16 f2bf(float f) {
  u32 u = __builtin_bit_cast(u32, f);
  u = (u + 0x7fffu + ((u >> 16) & 1u)) >> 16;   // RTNE
  return (u16)u;
}
static __device__ __forceinline__ u16 f2h(float a) {
  _Float16 ha = (_Float16)a;
  return __builtin_bit_cast(u16, ha);
}
static __device__ __forceinline__ float h2f(u16 a) {
  return (float)__builtin_bit_cast(_Float16, a);
}
static __device__ __forceinline__ float sigf(float x) {
  return 1.0f / (1.0f + __expf(-x));
}
static __device__ __forceinline__ float tanhfast(float x) {
  return 2.0f / (1.0f + __expf(-2.0f * x)) - 1.0f;
}

// ---------- kernel 1: pack W_hh_f (f32 [1024x256]) into f16 MFMA A-frag order --
// Wf[mt][kt][lane][j] f16, flat ((mt*8+kt)*64+lane)*8+j.
// Value = W[mt*16 + (lane&15)][kt*32 + (lane>>4)*8 + j].
__global__ __launch_bounds__(256) void k_prep(const float* __restrict__ whh,
                                              u16* __restrict__ Wf) {
  int cell = blockIdx.x * 256 + threadIdx.x;  // 32768 cells, 8 f16 each
  int mt = cell >> 9, kt = (cell >> 6) & 7, l = cell & 63;
  int gr = mt * 16 + (l & 15);
  int c0 = kt * 32 + (l >> 4) * 8;
  const float4* src = (const float4*)(whh + (size_t)gr * 256 + c0);
  float4 a = src[0], b = src[1];
  u16 o[8] = { f2h(a.x), f2h(a.y), f2h(a.z), f2h(a.w),
               f2h(b.x), f2h(b.y), f2h(b.z), f2h(b.w) };
  uint4* dst = (uint4*)(Wf + (size_t)cell * 8);
  *dst = *(uint4*)o;
}

// ---------- kernel 2: xproj via bf16 MFMA, output f16 in k_rnn D-frag order ---
// xp2[t][bg][mt][lane][r], flat ((((t*4+bg)*64+mt)*64+lane)*4+r), f16.
#define LDSPITCH 264
__global__ __launch_bounds__(256) void k_xproj(const int* __restrict__ x,
                                               const float* __restrict__ emb,
                                               const float* __restrict__ wih,
                                               const float* __restrict__ bih,
                                               const float* __restrict__ bhh,
                                               u16* __restrict__ xp2) {
  __shared__ u16 smA[64 * LDSPITCH];
  __shared__ u16 smB[64 * LDSPITCH];
  const int tn = blockIdx.x, t = blockIdx.y;
  const int tid = threadIdx.x;
  const int r = tid >> 2, q4 = tid & 3;

  { // stage A: emb rows (batch r, timestep t), fp32 -> bf16
    int eidx = x[r * T_LEN + t];
    const float4* src = (const float4*)(emb + (size_t)eidx * EDIM + q4 * 64);
    u16* dst = smA + r * LDSPITCH + q4 * 64;
    #pragma unroll
    for (int i = 0; i < 16; ++i) {
      float4 v = src[i];
      uint2 p;
      p.x = (u32)f2bf(v.x) | ((u32)f2bf(v.y) << 16);
      p.y = (u32)f2bf(v.z) | ((u32)f2bf(v.w) << 16);
      *(uint2*)&dst[i * 4] = p;
    }
  }
  { // stage B: w_ih rows g = tn*64 + r
    const float4* src = (const float4*)(wih + (size_t)(tn * 64 + r) * EDIM + q4 * 64);
    u16* dst = smB + r * LDSPITCH + q4 * 64;
    #pragma unroll
    for (int i = 0; i < 16; ++i) {
      float4 v = src[i];
      uint2 p;
      p.x = (u32)f2bf(v.x) | ((u32)f2bf(v.y) << 16);
      p.y = (u32)f2bf(v.z) | ((u32)f2bf(v.w) << 16);
      *(uint2*)&dst[i * 4] = p;
    }
  }
  __syncthreads();

  const int wv = tid >> 6, lane = tid & 63;
  const int lm = lane & 15, q = lane >> 4;
  f32x4 acc[4];
  #pragma unroll
  for (int nt = 0; nt < 4; ++nt) acc[nt] = (f32x4){0.f, 0.f, 0.f, 0.f};

  const u16* pa = smA + (wv * 16 + lm) * LDSPITCH + q * 8;
  const u16* pb = smB + lm * LDSPITCH + q * 8;
  #pragma unroll
  for (int ks = 0; ks < 8; ++ks) {
    short8 av = *(const short8*)(pa + ks * 32);
    #pragma unroll
    for (int nt = 0; nt < 4; ++nt) {
      short8 bv = *(const short8*)(pb + nt * 16 * LDSPITCH + ks * 32);
      acc[nt] = __builtin_amdgcn_mfma_f32_16x16x32_bf16(av, bv, acc[nt], 0, 0, 0);
    }
  }
  // D: row = batch = wv*16 + q*4 + rr, col = gate = tn*64 + nt*16 + lm.
  #pragma unroll
  for (int nt = 0; nt < 4; ++nt) {
    int g = tn * 64 + nt * 16 + lm;
    float bias = bih[g] + bhh[g];
    int mt = g >> 4, qd = (g & 15) >> 2, rb = g & 3;
    #pragma unroll
    for (int rr = 0; rr < 4; ++rr) {
      int bl = q * 4 + rr;   // batch-in-group; bg = wv
      size_t idx = ((((size_t)t * 4 + wv) * 64 + mt) * 64 + (qd * 16 + bl)) * 4 + rb;
      xp2[idx] = f2h(acc[nt][rr] + bias);
    }
  }
}

// ---------- kernel 3: recurrence, 4 WGs x 512 thr, NO cross-WG sync ----------
// WG bg owns batches [bg*16, +16). Wave v owns h row-blocks j = 2v, 2v+1
// (m-tiles mt = q*16 + j, q = gate). Two passes (p = j parity) of 4 m-tiles.
// Weight frags per (pass q, kt): 18 RF (pinned) + 9 LDS + 5 streamed-from-L2.
// h lives in LDS (single buffer, deferred write after a barrier).
__global__ __launch_bounds__(512, 2) void k_rnn(const u16* __restrict__ Wf,
                                                const u16* __restrict__ xp2,
                                                float* __restrict__ hf) {
  extern __shared__ u16 sm[];          // [0,147456): weight frags; then h buf
  u16* smW = sm;
  u16* smH = sm + 73728;               // byte 147456; h[batch16][row256] pitch 264
  const int bg = blockIdx.x;
  const int tid = threadIdx.x;
  const int v = tid >> 6, l = tid & 63;
  const int bl = l & 15, qd = l >> 4;

  // frag placement: 0=RF, 1=LDS, 2=streamed  (per pass: 18/9/5)
  constexpr int KIND[4][8] = {
    {0,0,0,0,0,1,1,2},
    {0,0,0,0,0,1,1,2},
    {0,0,0,0,1,1,2,2},
    {0,0,0,0,1,1,1,2}};
  constexpr int IDX[4][8] = {
    {0,1,2,3,4, 0,1, 0},
    {5,6,7,8,9, 2,3, 1},
    {10,11,12,13, 4,5, 2,3},
    {14,15,16,17, 6,7,8, 4}};

  // ---- stage resident + LDS weight frags ----
  half8 Wr[2][18];
  #pragma unroll
  for (int p = 0; p < 2; ++p) {
    int j = 2 * v + p;
    #pragma unroll
    for (int q = 0; q < 4; ++q)
      #pragma unroll
      for (int kt = 0; kt < 8; ++kt) {
        const u16* src = Wf + ((size_t)((q * 16 + j) * 8 + kt) * 64 + l) * 8;
        if (KIND[q][kt] == 0) {
          Wr[p][IDX[q][kt]] = *(const half8*)src;
        } else if (KIND[q][kt] == 1) {
          uint4 tv = *(const uint4*)src;
          *(uint4*)(smW + ((size_t)(v * 18 + p * 9 + IDX[q][kt]) * 64 + l) * 8) = tv;
        }
      }
  }
  // opacity pin: forbid rematerialization of the resident frags
  #pragma unroll
  for (int p = 0; p < 2; ++p) {
    asm volatile("" : "+v"(Wr[p][0]), "+v"(Wr[p][1]), "+v"(Wr[p][2]),
                      "+v"(Wr[p][3]), "+v"(Wr[p][4]), "+v"(Wr[p][5]),
                      "+v"(Wr[p][6]), "+v"(Wr[p][7]), "+v"(Wr[p][8]));
    asm volatile("" : "+v"(Wr[p][9]), "+v"(Wr[p][10]), "+v"(Wr[p][11]),
                      "+v"(Wr[p][12]), "+v"(Wr[p][13]), "+v"(Wr[p][14]),
                      "+v"(Wr[p][15]), "+v"(Wr[p][16]), "+v"(Wr[p][17]));
  }

  { // zero h buffer (16*264 u16 = 2112 u32)
    u32* hz = (u32*)smH;
    #pragma unroll
    for (int k = 0; k < 5; ++k) { int i = tid + k * 512; if (i < 2112) hz[i] = 0; }
  }
  __syncthreads();

  float c[2][4];
  #pragma unroll
  for (int p = 0; p < 2; ++p)
    #pragma unroll
    for (int r = 0; r < 4; ++r) c[p][r] = 0.f;

  const u16* xb = xp2 + (size_t)bg * 16384 + (size_t)l * 4;   // += 65536 per t
  const u16* wfl = Wf + (size_t)l * 8;
  const u16* hrd = smH + bl * 264 + qd * 8;                   // B-frag base
  u16*       hwr = smH + bl * 264 + 32 * v + qd * 4;          // + 16*p : h write

  for (int t = 0; t < T_LEN; ++t) {
    u32 hpk[2][2];
    #pragma unroll
    for (int p = 0; p < 2; ++p) {
      const int j = 2 * v + p;
      // streamed frags (L2-resident; issued up front, consumed late in kt loop)
      uint4 As[5];
      #pragma unroll
      for (int q = 0; q < 4; ++q)
        #pragma unroll
        for (int kt = 0; kt < 8; ++kt)
          if (KIND[q][kt] == 2)
            As[IDX[q][kt]] = *(const uint4*)(wfl + (size_t)((q * 16 + j) * 8 + kt) * 512);
      // xproj frags for this pass
      uint2 xv[4];
      #pragma unroll
      for (int q = 0; q < 4; ++q)
        xv[q] = *(const uint2*)(xb + (size_t)(q * 16 + j) * 256);

      f32x4 acc[4];
      #pragma unroll
      for (int q = 0; q < 4; ++q) acc[q] = (f32x4){0.f, 0.f, 0.f, 0.f};
      #pragma unroll
      for (int kt = 0; kt < 8; ++kt) {
        half8 Bf = *(const half8*)(hrd + kt * 32);
        #pragma unroll
        for (int q = 0; q < 4; ++q) {
          half8 Af;
          if (KIND[q][kt] == 0)
            Af = Wr[p][IDX[q][kt]];
          else if (KIND[q][kt] == 1)
            Af = *(const half8*)(smW + ((size_t)(v * 18 + p * 9 + IDX[q][kt]) * 64 + l) * 8);
          else
            Af = __builtin_bit_cast(half8, As[IDX[q][kt]]);
          acc[q] = __builtin_amdgcn_mfma_f32_16x16x32_f16(Af, Bf, acc[q], 0, 0, 0);
        }
      }
      // fold xp + gates; rows j*16 + qd*4 + r, batch bg*16 + bl
      u16 hh[4];
      #pragma unroll
      for (int r = 0; r < 4; ++r) {
        float zi = acc[0][r] + h2f((u16)(xv[0].x >> (16 * (r & 1)))) * 0.f; // placeholder avoided
        zi = acc[0][r];
        float zf = acc[1][r], zg = acc[2][r], zo = acc[3][r];
        u32 xw0 = (r < 2) ? xv[0].x : xv[0].y;
        u32 xw1 = (r < 2) ? xv[1].x : xv[1].y;
        u32 xw2 = (r < 2) ? xv[2].x : xv[2].y;
        u32 xw3 = (r < 2) ? xv[3].x : xv[3].y;
        int sh = 16 * (r & 1);
        zi += h2f((u16)(xw0 >> sh));
        zf += h2f((u16)(xw1 >> sh));
        zg += h2f((u16)(xw2 >> sh));
        zo += h2f((u16)(xw3 >> sh));
        c[p][r] = sigf(zf) * c[p][r] + sigf(zi) * tanhfast(zg);
        float hn = sigf(zo) * tanhfast(c[p][r]);
        hh[r] = f2h(hn);
        if (t == T_LEN - 1)
          hf[(size_t)(bg * 16 + bl) * 256 + j * 16 + qd * 4 + r] = hn;
      }
      hpk[p][0] = (u32)hh[0] | ((u32)hh[1] << 16);
      hpk[p][1] = (u32)hh[2] | ((u32)hh[3] << 16);
    }
    // all h(t) reads (MFMAs) done in both passes -> safe to overwrite
    __syncthreads();
    #pragma unroll
    for (int p = 0; p < 2; ++p)
      *(uint2*)(hwr + 16 * p) = make_uint2(hpk[p][0], hpk[p][1]);
    __syncthreads();
    xb += 65536;
  }
}

// ---------- kernel 4: backward single step + fc1 + fc2 ----------
__global__ __launch_bounds__(256) void k_tail(const int* __restrict__ x,
                                              const float* __restrict__ emb,
                                              const float* __restrict__ wihb,
                                              const float* __restrict__ bihb,
                                              const float* __restrict__ bhhb,
                                              const float* __restrict__ fc1w,
                                              const float* __restrict__ fc1b,
                                              const float* __restrict__ fc2w,
                                              const float* __restrict__ fc2b,
                                              const float* __restrict__ hf,
                                              float* __restrict__ out) {
  const int b = blockIdx.x, tid = threadIdx.x;
  __shared__ float e[EDIM], hb[HDIM], hfl[HDIM], f1[24];
  e[tid]   = emb[(size_t)x[b * T_LEN + (T_LEN - 1)] * EDIM + tid];
  hfl[tid] = hf[b * HDIM + tid];
  __syncthreads();

  float z[4];
  #pragma unroll
  for (int gq = 0; gq < 4; ++gq) {
    int g = gq * HDIM + tid;
    float s = bihb[g] + bhhb[g];
    const float4* wr = (const float4*)(wihb + (size_t)g * EDIM);
    #pragma unroll 8
    for (int k = 0; k < 64; ++k) {
      float4 w = wr[k];
      s += w.x * e[4 * k] + w.y * e[4 * k + 1] + w.z * e[4 * k + 2] + w.w * e[4 * k + 3];
    }
    z[gq] = s;
  }
  float cb = sigf(z[0]) * tanhfast(z[2]);   // c0 = 0
  hb[tid] = sigf(z[3]) * tanhfast(cb);
  __syncthreads();

  if (tid < 24) {
    float s = fc1b[tid];
    const float* w = fc1w + tid * 512;
    #pragma unroll 8
    for (int k = 0; k < HDIM; ++k) s += w[k] * hfl[k] + w[HDIM + k] * hb[k];
    f1[tid] = fmaxf(s, 0.f);
  }
  __syncthreads();
  if (tid < 2) {
    float s = fc2b[tid];
    #pragma unroll
    for (int k = 0; k < 24; ++k) s += fc2w[tid * 24 + k] * f1[k];
    out[b * 2 + tid] = s;
  }
}

// ---------- launch ----------
extern "C" void kernel_launch(void* const* d_in, const int* in_sizes, int n_in,
                              void* d_out, int out_size, void* d_ws, size_t ws_size,
                              hipStream_t stream) {
  const int*   x     = (const int*)  d_in[0];
  const float* emb   = (const float*)d_in[1];
  const float* wih_f = (const float*)d_in[2];
  const float* whh_f = (const float*)d_in[3];
  const float* bih_f = (const float*)d_in[4];
  const float* bhh_f = (const float*)d_in[5];
  const float* wih_b = (const float*)d_in[6];
  // d_in[7] = w_hh_b: unused (backward runs exactly one step from zero state)
  const float* bih_b = (const float*)d_in[8];
  const float* bhh_b = (const float*)d_in[9];
  const float* fc1w  = (const float*)d_in[10];
  const float* fc1b  = (const float*)d_in[11];
  const float* fc2w  = (const float*)d_in[12];
  const float* fc2b  = (const float*)d_in[13];
  float* out = (float*)d_out;

  // workspace: xp2 64 MiB | Wf 512 KiB | hf 64 KiB
  char* ws = (char*)d_ws;
  u16*   xp2 = (u16*)ws;
  u16*   Wf  = (u16*)(ws + 67108864);
  float* hf  = (float*)(ws + 67108864 + 524288);

  k_prep <<<128, 256, 0, stream>>>(whh_f, Wf);
  k_xproj<<<dim3(16, 512), 256, 0, stream>>>(x, emb, wih_f, bih_f, bhh_f, xp2);
  k_rnn  <<<4, 512, 155904, stream>>>(Wf, xp2, hf);
  k_tail <<<BATCH, 256, 0, stream>>>(x, emb, wih_b, bih_b, bhh_b,
                                     fc1w, fc1b, fc2w, fc2b, hf, out);
}

// Round 6
// 2301.782 us; speedup vs baseline: 1.5004x; 1.0679x over previous
//
#include <hip/hip_runtime.h>

typedef unsigned int  u32;
typedef unsigned short u16;
typedef unsigned long long u64;
typedef _Float16 half8 __attribute__((ext_vector_type(8)));
typedef short   short8 __attribute__((ext_vector_type(8)));
typedef float   f32x4  __attribute__((ext_vector_type(4)));

#define T_LEN 512
#define BATCH 64
#define EDIM  256
#define HDIM  256
#define G4    1024   // 4*H gate rows

// ---------- numeric helpers ----------
static __device__ __forceinline__ u16 f2bf(float f) {
  u32 u = __builtin_bit_cast(u32, f);
  u = (u + 0x7fffu + ((u >> 16) & 1u)) >> 16;   // RTNE
  return (u16)u;
}
static __device__ __forceinline__ u16 f2h(float a) {
  _Float16 ha = (_Float16)a;
  return __builtin_bit_cast(u16, ha);
}
static __device__ __forceinline__ float h2f(u16 a) {
  return (float)__builtin_bit_cast(_Float16, a);
}
static __device__ __forceinline__ float sigf(float x) {
  return 1.0f / (1.0f + __expf(-x));
}
static __device__ __forceinline__ float tanhfast(float x) {
  return 2.0f / (1.0f + __expf(-2.0f * x)) - 1.0f;
}

// ---------- kernel 1: pack W_hh_f into f16 MFMA A-frag order -----------------
// Wf[mt][kt][lane][j]: flat ((mt*8+kt)*64+lane)*8+j; value =
// W[mt*16+(lane&15)][kt*32+(lane>>4)*8+j].  Also pack kt==7 frags contiguously:
// Wst[(j16*4+q)][lane][j] where mt = q*16 + j16  (1 KB stride -> imm offsets).
__global__ __launch_bounds__(256) void k_prep(const float* __restrict__ whh,
                                              u16* __restrict__ Wf,
                                              u16* __restrict__ Wst) {
  int cell = blockIdx.x * 256 + threadIdx.x;  // 32768 cells, 8 f16 each
  int mt = cell >> 9, kt = (cell >> 6) & 7, l = cell & 63;
  int gr = mt * 16 + (l & 15);
  int c0 = kt * 32 + (l >> 4) * 8;
  const float4* src = (const float4*)(whh + (size_t)gr * 256 + c0);
  float4 a = src[0], b = src[1];
  u16 o[8] = { f2h(a.x), f2h(a.y), f2h(a.z), f2h(a.w),
               f2h(b.x), f2h(b.y), f2h(b.z), f2h(b.w) };
  *(uint4*)(Wf + (size_t)cell * 8) = *(uint4*)o;
  if (kt == 7) {
    int q = mt >> 4, j16 = mt & 15;
    *(uint4*)(Wst + ((size_t)(j16 * 4 + q) * 64 + l) * 8) = *(uint4*)o;
  }
}

// ---------- kernel 2: xproj via bf16 MFMA, f16 out in k_rnn D-frag order -----
// xp2[t][bg][mt'][lane][r] with mt' = j16*4 + q  (q=gate, j16=row-block).
#define LDSPITCH 264
__global__ __launch_bounds__(256) void k_xproj(const int* __restrict__ x,
                                               const float* __restrict__ emb,
                                               const float* __restrict__ wih,
                                               const float* __restrict__ bih,
                                               const float* __restrict__ bhh,
                                               u16* __restrict__ xp2) {
  __shared__ u16 smA[64 * LDSPITCH];
  __shared__ u16 smB[64 * LDSPITCH];
  const int tn = blockIdx.x, t = blockIdx.y;
  const int tid = threadIdx.x;
  const int r = tid >> 2, q4 = tid & 3;

  { // stage A: emb rows (batch r, timestep t), fp32 -> bf16
    int eidx = x[r * T_LEN + t];
    const float4* src = (const float4*)(emb + (size_t)eidx * EDIM + q4 * 64);
    u16* dst = smA + r * LDSPITCH + q4 * 64;
    #pragma unroll
    for (int i = 0; i < 16; ++i) {
      float4 v = src[i];
      uint2 p;
      p.x = (u32)f2bf(v.x) | ((u32)f2bf(v.y) << 16);
      p.y = (u32)f2bf(v.z) | ((u32)f2bf(v.w) << 16);
      *(uint2*)&dst[i * 4] = p;
    }
  }
  { // stage B: w_ih rows g = tn*64 + r
    const float4* src = (const float4*)(wih + (size_t)(tn * 64 + r) * EDIM + q4 * 64);
    u16* dst = smB + r * LDSPITCH + q4 * 64;
    #pragma unroll
    for (int i = 0; i < 16; ++i) {
      float4 v = src[i];
      uint2 p;
      p.x = (u32)f2bf(v.x) | ((u32)f2bf(v.y) << 16);
      p.y = (u32)f2bf(v.z) | ((u32)f2bf(v.w) << 16);
      *(uint2*)&dst[i * 4] = p;
    }
  }
  __syncthreads();

  const int wv = tid >> 6, lane = tid & 63;
  const int lm = lane & 15, q = lane >> 4;
  f32x4 acc[4];
  #pragma unroll
  for (int nt = 0; nt < 4; ++nt) acc[nt] = (f32x4){0.f, 0.f, 0.f, 0.f};

  const u16* pa = smA + (wv * 16 + lm) * LDSPITCH + q * 8;
  const u16* pb = smB + lm * LDSPITCH + q * 8;
  #pragma unroll
  for (int ks = 0; ks < 8; ++ks) {
    short8 av = *(const short8*)(pa + ks * 32);
    #pragma unroll
    for (int nt = 0; nt < 4; ++nt) {
      short8 bv = *(const short8*)(pb + nt * 16 * LDSPITCH + ks * 32);
      acc[nt] = __builtin_amdgcn_mfma_f32_16x16x32_bf16(av, bv, acc[nt], 0, 0, 0);
    }
  }
  // D: row = batch = wv*16+q*4+rr, col = gate row g = tn*64+nt*16+lm.
  #pragma unroll
  for (int nt = 0; nt < 4; ++nt) {
    int g = tn * 64 + nt * 16 + lm;
    float bias = bih[g] + bhh[g];
    int gq = g >> 8, j16 = (g >> 4) & 15, qd = (g & 15) >> 2, rb = g & 3;
    int mtp = j16 * 4 + gq;
    #pragma unroll
    for (int rr = 0; rr < 4; ++rr) {
      int bl = q * 4 + rr;   // batch-in-group; bg = wv
      size_t idx = ((((size_t)t * 4 + wv) * 64 + mtp) * 64 + (qd * 16 + bl)) * 4 + rb;
      xp2[idx] = f2h(acc[nt][rr] + bias);
    }
  }
}

// ---------- kernel 3: recurrence, 4 WGs x 512 thr, no cross-WG sync ----------
// WG bg owns batches [bg*16,+16). Wave v owns row-blocks j = 2v,2v+1
// (m-tiles mt = q*16 + j). Two passes p. Weights: kt0-4 RF (40 frags, pinned),
// kt5-6 LDS (16 frags, 128 KB), kt7 streamed from contiguous Wst (imm offsets).
// h double-buffered in LDS -> ONE barrier per step.
__global__ __launch_bounds__(512, 2) void k_rnn(const u16* __restrict__ Wf,
                                                const u16* __restrict__ Wst,
                                                const u16* __restrict__ xp2,
                                                float* __restrict__ hf) {
  extern __shared__ u16 sm[];
  u16* smW = sm;               // 65536 u16 = 128 KB (8 waves x 16 frags x 1 KB)
  u16* smH = sm + 65536;       // 2 x 4224 u16 (pitch 264) = 16.5 KB
  const int bg = blockIdx.x;
  const int tid = threadIdx.x;
  const int v = tid >> 6, l = tid & 63;
  const int bl = l & 15, qd = l >> 4;

  // ---- stage resident (kt0-4) and LDS (kt5-6) weight frags ----
  half8 Wr[2][4][5];
  #pragma unroll
  for (int p = 0; p < 2; ++p) {
    int j = 2 * v + p;
    #pragma unroll
    for (int q = 0; q < 4; ++q) {
      #pragma unroll
      for (int kt = 0; kt < 5; ++kt)
        Wr[p][q][kt] = *(const half8*)(Wf + ((size_t)((q * 16 + j) * 8 + kt) * 64 + l) * 8);
      #pragma unroll
      for (int kt = 5; kt < 7; ++kt) {
        uint4 tv = *(const uint4*)(Wf + ((size_t)((q * 16 + j) * 8 + kt) * 64 + l) * 8);
        *(uint4*)(smW + ((size_t)(v * 16 + (p * 4 + q) * 2 + (kt - 5)) * 64 + l) * 8) = tv;
      }
    }
  }
  // opacity pin: values unknown -> rematerialization from Wf illegal
  #pragma unroll
  for (int p = 0; p < 2; ++p)
    #pragma unroll
    for (int q = 0; q < 4; ++q)
      asm volatile("" : "+v"(Wr[p][q][0]), "+v"(Wr[p][q][1]), "+v"(Wr[p][q][2]),
                        "+v"(Wr[p][q][3]), "+v"(Wr[p][q][4]));

  { // zero h dbuf (2 x 4224 u16 = 4224 u32)
    u32* hz = (u32*)smH;
    #pragma unroll
    for (int k = 0; k < 9; ++k) { int i = tid + k * 512; if (i < 4224) hz[i] = 0; }
  }
  __syncthreads();

  float c[2][4];
  #pragma unroll
  for (int p = 0; p < 2; ++p)
    #pragma unroll
    for (int r = 0; r < 4; ++r) c[p][r] = 0.f;

  const u16* xbase = xp2 + (size_t)bg * 16384 + (size_t)l * 4;  // += 65536 per t
  const u16* wst_l = Wst + (size_t)l * 8;
  const u16* hrd0 = smH + bl * 264 + qd * 8;
  u16*       hwr0 = smH + bl * 264 + qd * 4;

  for (int t = 0; t < T_LEN; ++t) {
    const u16* hb = hrd0 + (t & 1) * 4224;
    u16*       hw = hwr0 + ((t + 1) & 1) * 4224;
    #pragma unroll
    for (int p = 0; p < 2; ++p) {
      const int j = 2 * v + p;
      // stream kt7 frags + xv: one base each, 1KB-stride imm offsets;
      // consumed >=7 MFMA-kts later -> latency hidden.
      const u16* wp = wst_l + j * 2048;
      uint4 As0 = *(const uint4*)(wp);
      uint4 As1 = *(const uint4*)(wp + 512);
      uint4 As2 = *(const uint4*)(wp + 1024);
      uint4 As3 = *(const uint4*)(wp + 1536);
      const u16* xb = xbase + j * 1024;
      uint2 xv0 = *(const uint2*)(xb);
      uint2 xv1 = *(const uint2*)(xb + 256);
      uint2 xv2 = *(const uint2*)(xb + 512);
      uint2 xv3 = *(const uint2*)(xb + 768);

      f32x4 acc[4];
      #pragma unroll
      for (int q = 0; q < 4; ++q) acc[q] = (f32x4){0.f, 0.f, 0.f, 0.f};
      #pragma unroll
      for (int kt = 0; kt < 8; ++kt) {
        half8 Bf = *(const half8*)(hb + kt * 32);
        #pragma unroll
        for (int q = 0; q < 4; ++q) {
          half8 Af;
          if (kt < 5)
            Af = Wr[p][q][kt];
          else if (kt < 7)
            Af = *(const half8*)(smW + ((size_t)(v * 16 + (p * 4 + q) * 2 + (kt - 5)) * 64 + l) * 8);
          else
            Af = __builtin_bit_cast(half8, q == 0 ? As0 : q == 1 ? As1 : q == 2 ? As2 : As3);
          acc[q] = __builtin_amdgcn_mfma_f32_16x16x32_f16(Af, Bf, acc[q], 0, 0, 0);
        }
      }
      // fold xp + gates; rows j*16 + qd*4 + r, batch bg*16 + bl
      u16 hh[4];
      #pragma unroll
      for (int r = 0; r < 4; ++r) {
        u32 x0 = (r < 2) ? xv0.x : xv0.y;
        u32 x1 = (r < 2) ? xv1.x : xv1.y;
        u32 x2 = (r < 2) ? xv2.x : xv2.y;
        u32 x3 = (r < 2) ? xv3.x : xv3.y;
        const int sh = 16 * (r & 1);
        float zi = acc[0][r] + h2f((u16)(x0 >> sh));
        float zf = acc[1][r] + h2f((u16)(x1 >> sh));
        float zg = acc[2][r] + h2f((u16)(x2 >> sh));
        float zo = acc[3][r] + h2f((u16)(x3 >> sh));
        c[p][r] = sigf(zf) * c[p][r] + sigf(zi) * tanhfast(zg);
        float hn = sigf(zo) * tanhfast(c[p][r]);
        hh[r] = f2h(hn);
        if (t == T_LEN - 1)
          hf[(size_t)(bg * 16 + bl) * 256 + j * 16 + qd * 4 + r] = hn;
      }
      *(uint2*)(hw + j * 16) = make_uint2((u32)hh[0] | ((u32)hh[1] << 16),
                                          (u32)hh[2] | ((u32)hh[3] << 16));
    }
    __syncthreads();   // single barrier: next step reads the buffer just written
    xbase += 65536;
  }
}

// ---------- kernel 4: backward single step + fc1 + fc2 ----------
__global__ __launch_bounds__(256) void k_tail(const int* __restrict__ x,
                                              const float* __restrict__ emb,
                                              const float* __restrict__ wihb,
                                              const float* __restrict__ bihb,
                                              const float* __restrict__ bhhb,
                                              const float* __restrict__ fc1w,
                                              const float* __restrict__ fc1b,
                                              const float* __restrict__ fc2w,
                                              const float* __restrict__ fc2b,
                                              const float* __restrict__ hf,
                                              float* __restrict__ out) {
  const int b = blockIdx.x, tid = threadIdx.x;
  __shared__ float e[EDIM], hb[HDIM], hfl[HDIM], f1[24];
  e[tid]   = emb[(size_t)x[b * T_LEN + (T_LEN - 1)] * EDIM + tid];
  hfl[tid] = hf[b * HDIM + tid];
  __syncthreads();

  float z[4];
  #pragma unroll
  for (int gq = 0; gq < 4; ++gq) {
    int g = gq * HDIM + tid;
    float s = bihb[g] + bhhb[g];
    const float4* wr = (const float4*)(wihb + (size_t)g * EDIM);
    #pragma unroll 8
    for (int k = 0; k < 64; ++k) {
      float4 w = wr[k];
      s += w.x * e[4 * k] + w.y * e[4 * k + 1] + w.z * e[4 * k + 2] + w.w * e[4 * k + 3];
    }
    z[gq] = s;
  }
  float cb = sigf(z[0]) * tanhfast(z[2]);   // c0 = 0
  hb[tid] = sigf(z[3]) * tanhfast(cb);
  __syncthreads();

  if (tid < 24) {
    float s = fc1b[tid];
    const float* w = fc1w + tid * 512;
    #pragma unroll 8
    for (int k = 0; k < HDIM; ++k) s += w[k] * hfl[k] + w[HDIM + k] * hb[k];
    f1[tid] = fmaxf(s, 0.f);
  }
  __syncthreads();
  if (tid < 2) {
    float s = fc2b[tid];
    #pragma unroll
    for (int k = 0; k < 24; ++k) s += fc2w[tid * 24 + k] * f1[k];
    out[b * 2 + tid] = s;
  }
}

// ---------- launch ----------
extern "C" void kernel_launch(void* const* d_in, const int* in_sizes, int n_in,
                              void* d_out, int out_size, void* d_ws, size_t ws_size,
                              hipStream_t stream) {
  const int*   x     = (const int*)  d_in[0];
  const float* emb   = (const float*)d_in[1];
  const float* wih_f = (const float*)d_in[2];
  const float* whh_f = (const float*)d_in[3];
  const float* bih_f = (const float*)d_in[4];
  const float* bhh_f = (const float*)d_in[5];
  const float* wih_b = (const float*)d_in[6];
  // d_in[7] = w_hh_b: unused (backward runs exactly one step from zero state)
  const float* bih_b = (const float*)d_in[8];
  const float* bhh_b = (const float*)d_in[9];
  const float* fc1w  = (const float*)d_in[10];
  const float* fc1b  = (const float*)d_in[11];
  const float* fc2w  = (const float*)d_in[12];
  const float* fc2b  = (const float*)d_in[13];
  float* out = (float*)d_out;

  // workspace: xp2 64 MiB | Wf 512 KiB | Wst 64 KiB | hf 64 KiB
  char* ws = (char*)d_ws;
  u16*   xp2 = (u16*)ws;
  u16*   Wf  = (u16*)(ws + 67108864);
  u16*   Wst = (u16*)(ws + 67108864 + 524288);
  float* hf  = (float*)(ws + 67108864 + 524288 + 65536);

  k_prep <<<128, 256, 0, stream>>>(whh_f, Wf, Wst);
  k_xproj<<<dim3(16, 512), 256, 0, stream>>>(x, emb, wih_f, bih_f, bhh_f, xp2);
  k_rnn  <<<4, 512, 147968, stream>>>(Wf, Wst, xp2, hf);
  k_tail <<<BATCH, 256, 0, stream>>>(x, emb, wih_b, bih_b, bhh_b,
                                     fc1w, fc1b, fc2w, fc2b, hf, out);
}